// Round 7
// baseline (93.971 us; speedup 1.0000x reference)
//
#include <hip/hip_runtime.h>
#include <hip/hip_bf16.h>
#include <stdint.h>
#include <float.h>

// ItemEncoder: h = relu(concat(emb[type], item) @ W + b); out = max over item axis.
// BS=32, NA=128, NI=128, F=11, TH=32, K=43 (pad->48), NH=128.
//
// R7: max-TLP discriminator. 1-wave workgroups (grid 4096 x 64), ZERO barriers,
// ZERO LDS. Each wave owns one (b,n): feats read directly from global (lane-sliced
// scalar loads, full line utilization), emb via aligned float4, B-frags from Bpre
// (L2-resident). 8-12 independent waves/CU hide all load latency in rotation.
//  - prep_b unchanged: W -> f16 MFMA B-fragments in d_ws (12 KB), coalesced.

#define NITEM  128
#define NFEAT  11
#define NTH    32
#define NH     128
#define KREAL  43
#define KSTEPS 3            // K = 48 = 3 x 16
#define SLABDW (NITEM * NFEAT)   // 1408 dwords per bn

typedef __attribute__((ext_vector_type(8)))  _Float16 half8;
typedef __attribute__((ext_vector_type(2)))  __fp16   fp16x2;   // cvt_pkrtz result type
typedef __attribute__((ext_vector_type(16))) float    f32x16;

union H8 { half8 h8; fp16x2 h2[4]; };

// ---- pre-kernel: build B fragments (frag = kk*4+n, 64 lanes each, half8/lane) ----
__global__ __launch_bounds__(64) void prep_b(const float* __restrict__ W,
                                             _Float16* __restrict__ Bpre) {
    const int frag = blockIdx.x;          // 0..11 = kk*4 + n
    const int kk   = frag >> 2;
    const int n    = frag & 3;
    const int lane = threadIdx.x;         // 0..63
    const int col  = n * 32 + (lane & 31);
    const int k0   = kk * 16 + (lane >> 5) * 8;
    half8 pk;
    #pragma unroll
    for (int q = 0; q < 8; ++q) {
        const int k = k0 + q;
        pk[q] = (_Float16)((k < KREAL) ? W[k * NH + col] : 0.0f);
    }
    ((half8*)Bpre)[frag * 64 + lane] = pk;
}

__global__ __launch_bounds__(64, 2) void item_encoder(
    const int*      __restrict__ item_type,  // [BS*NA*NI] int32
    const float*    __restrict__ item,       // [BS*NA*NI*NFEAT]
    const float*    __restrict__ emb,        // [18*32]
    const _Float16* __restrict__ Bpre,       // [12*64*8] f16 frags
    const float*    __restrict__ bias,       // [128]
    float*          __restrict__ out)        // [BS*NA*NH]
{
    const int lane = threadIdx.x;            // 0..63 (one wave per block)
    const int l31  = lane & 31;
    const int lhi  = lane >> 5;              // k-half selector
    const int bn   = blockIdx.x;             // 0..4095

    // ---- B fragments: 12 coalesced 16B loads/lane (L2-resident after first waves) ----
    half8 bf[KSTEPS][4];
    #pragma unroll
    for (int kk = 0; kk < KSTEPS; ++kk)
        #pragma unroll
        for (int n = 0; n < 4; ++n)
            bf[kk][n] = ((const half8*)Bpre)[(kk * 4 + n) * 64 + lane];

    // ---- ty for this wave's 4 row-blocks (lanes 32-63 mirror 0-31: broadcast) ----
    int ty[4];
    {
        const int* tb = item_type + (size_t)bn * NITEM + l31;
        #pragma unroll
        for (int rb = 0; rb < 4; ++rb) ty[rb] = tb[rb * 32];
    }

    float bias4[4];
    #pragma unroll
    for (int n = 0; n < 4; ++n) bias4[n] = bias[n * 32 + l31];

    const float* feat = item + (size_t)bn * SLABDW;

    float vm[4] = { -FLT_MAX, -FLT_MAX, -FLT_MAX, -FLT_MAX };

    // ---- 4 row-blocks, fully unrolled; each: 12 loads -> cvt -> 12 MFMA -> max ----
    #pragma unroll
    for (int rb = 0; rb < 4; ++rb) {
        const int r = rb * 32 + l31;         // this lane's item row

        // emb slices for a0 (k=0..15) and a1 (k=16..31): aligned float4s
        const float* eb = emb + ty[rb] * NTH + lhi * 8;
        const float4 e0 = *(const float4*)(eb);
        const float4 e1 = *(const float4*)(eb + 4);
        const float4 e2 = *(const float4*)(eb + 16);
        const float4 e3 = *(const float4*)(eb + 20);

        // feats straight from global, lane-sliced: lhi=0 -> f=0..7; lhi=1 -> f=8..10,+pad
        // (a2 covers k=32..47 i.e. f=0..15; f>=11 zero-padded)
        const float* fp = feat + r * NFEAT;
        float fv[8];
        #pragma unroll
        for (int q = 0; q < 8; ++q) {
            const int  f    = lhi ? ((q < 3) ? 8 + q : 10) : q;   // clamp addr in-row
            const bool dead = (lhi && q >= 3);
            const float x = fp[f];
            fv[q] = dead ? 0.0f : x;
        }

        H8 a0, a1, a2;
        a0.h2[0] = __builtin_amdgcn_cvt_pkrtz(e0.x, e0.y);
        a0.h2[1] = __builtin_amdgcn_cvt_pkrtz(e0.z, e0.w);
        a0.h2[2] = __builtin_amdgcn_cvt_pkrtz(e1.x, e1.y);
        a0.h2[3] = __builtin_amdgcn_cvt_pkrtz(e1.z, e1.w);
        a1.h2[0] = __builtin_amdgcn_cvt_pkrtz(e2.x, e2.y);
        a1.h2[1] = __builtin_amdgcn_cvt_pkrtz(e2.z, e2.w);
        a1.h2[2] = __builtin_amdgcn_cvt_pkrtz(e3.x, e3.y);
        a1.h2[3] = __builtin_amdgcn_cvt_pkrtz(e3.z, e3.w);
        a2.h2[0] = __builtin_amdgcn_cvt_pkrtz(fv[0], fv[1]);
        a2.h2[1] = __builtin_amdgcn_cvt_pkrtz(fv[2], fv[3]);
        a2.h2[2] = __builtin_amdgcn_cvt_pkrtz(fv[4], fv[5]);
        a2.h2[3] = __builtin_amdgcn_cvt_pkrtz(fv[6], fv[7]);

        f32x16 acc[4];
        #pragma unroll
        for (int n = 0; n < 4; ++n)
            #pragma unroll
            for (int rr = 0; rr < 16; ++rr) acc[n][rr] = 0.0f;

        #pragma unroll
        for (int n = 0; n < 4; ++n) acc[n] = __builtin_amdgcn_mfma_f32_32x32x16_f16(a0.h8, bf[0][n], acc[n], 0, 0, 0);
        #pragma unroll
        for (int n = 0; n < 4; ++n) acc[n] = __builtin_amdgcn_mfma_f32_32x32x16_f16(a1.h8, bf[1][n], acc[n], 0, 0, 0);
        #pragma unroll
        for (int n = 0; n < 4; ++n) acc[n] = __builtin_amdgcn_mfma_f32_32x32x16_f16(a2.h8, bf[2][n], acc[n], 0, 0, 0);

        // max over this row-block's 32 rows, fold into running col-max
        // C/D layout: col = lane&31, row = (reg&3) + 8*(reg>>2) + 4*(lane>>5)
        #pragma unroll
        for (int n = 0; n < 4; ++n) {
            float m = acc[n][0];
            #pragma unroll
            for (int rr = 1; rr < 16; ++rr) m = fmaxf(m, acc[n][rr]);
            m = fmaxf(m, __shfl_xor(m, 32));     // fold the two 16-row halves
            vm[n] = fmaxf(vm[n], m);
        }
    }

    // ---- store: lanes 0..31 hold the 128-col result for this bn ----
    if (lane < 32) {
        #pragma unroll
        for (int n = 0; n < 4; ++n)
            out[(size_t)bn * NH + n * 32 + l31] = fmaxf(vm[n] + bias4[n], 0.0f);
    }
}

extern "C" void kernel_launch(void* const* d_in, const int* in_sizes, int n_in,
                              void* d_out, int out_size, void* d_ws, size_t ws_size,
                              hipStream_t stream) {
    const int*   item_type = (const int*)  d_in[0];
    const float* item      = (const float*)d_in[1];
    const float* emb       = (const float*)d_in[2];
    const float* W         = (const float*)d_in[3];
    const float* bias      = (const float*)d_in[4];
    float*       out       = (float*)d_out;
    _Float16*    Bpre      = (_Float16*)d_ws;   // 12*64*8*2 = 12 KB

    prep_b<<<12, 64, 0, stream>>>(W, Bpre);
    item_encoder<<<32 * 128, 64, 0, stream>>>(item_type, item, emb, Bpre, bias, out);
}